// Round 1
// baseline (506.792 us; speedup 1.0000x reference)
//
#include <hip/hip_runtime.h>
#include <hip/hip_bf16.h>

#define NB 32
#define NS 2048
#define DIM 1024
#define NM (NB*NS)   // 65536 rows

typedef __attribute__((ext_vector_type(8))) short short8;
typedef __attribute__((ext_vector_type(4))) float f32x4;
typedef unsigned short us16;
typedef unsigned int   u32;

__device__ __forceinline__ float fast_tanh(float x){
  // tanh(x) = 1 - 2/(e^{2x}+1), e^{2x} via single v_exp_f32
  float e = __builtin_exp2f(x * 2.8853900817779268f); // 2*log2(e)
  return 1.0f - 2.0f/(e + 1.0f);
}

// split f32 into bf16 hi (truncated) + bf16 lo (residual); error ~2^-16 rel
__device__ __forceinline__ void split_bf16(float x, short &hi, short &lo){
  u32 u = __float_as_uint(x);
  float hf = __uint_as_float(u & 0xFFFF0000u);
  hi = (short)(u >> 16);
  lo = (short)(__float_as_uint(x - hf) >> 16);
}

// ---------------- Wb -> hi/lo bf16 ----------------
__global__ void k_split_wb(const float* __restrict__ wb,
                           us16* __restrict__ h, us16* __restrict__ l){
  int idx = (blockIdx.x*256 + threadIdx.x)*8;
  float4 v0 = *(const float4*)(wb + idx);
  float4 v1 = *(const float4*)(wb + idx + 4);
  float v[8] = {v0.x,v0.y,v0.z,v0.w,v1.x,v1.y,v1.z,v1.w};
  short8 hs, ls;
  #pragma unroll
  for(int j=0;j<8;j++){ short a,b; split_bf16(v[j],a,b); hs[j]=a; ls[j]=b; }
  *(short8*)(h + idx) = hs;
  *(short8*)(l + idx) = ls;
}

// ---------------- a = k @ Wa^T ----------------
__global__ void k_compute_a(const float* __restrict__ kin,
                            const float* __restrict__ wa,
                            float* __restrict__ avec){
  __shared__ float4 kl[256];
  const int b = blockIdx.x >> 2, oc = blockIdx.x & 3;
  const int t = threadIdx.x;
  kl[t] = *(const float4*)(kin + b*DIM + t*4);
  __syncthreads();
  const int o = oc*256 + t;
  const float4* wrow = (const float4*)(wa + (size_t)o*DIM);
  float acc = 0.f;
  for(int i=0;i<256;i++){
    float4 wv = wrow[i]; float4 kk = kl[i];
    acc += wv.x*kk.x + wv.y*kk.y + wv.z*kk.z + wv.w*kk.w;
  }
  avec[b*DIM + o] = acc;
}

// ---------------- main: b-tile GEMM (bf16x2 split, 3 MFMA passes) fused with
// tanh(a+b)*energy reduction -> per-column-tile score partials ----------------
__global__ __launch_bounds__(256)
void k_gemm_scores(const float* __restrict__ xs,
                   const us16* __restrict__ wbh,
                   const us16* __restrict__ wbl,
                   const float* __restrict__ avec,
                   const float* __restrict__ energy,
                   float* __restrict__ partial){
  __shared__ us16 Ah[128][40];   // pad to 40 (80B stride: 2-way bank alias = free)
  __shared__ us16 Al[128][40];
  __shared__ us16 Bh[128][40];
  __shared__ us16 Bl[128][40];

  const int bid = blockIdx.x;
  const int ct = bid & 7, rt = bid >> 3;      // 8 col tiles fast -> L2/L3 A reuse
  const int t  = threadIdx.x;
  const int w  = t >> 6, lane = t & 63;
  const int wr = w >> 1, wc = w & 1;          // wave quadrant (64x64)
  const int lm = lane & 15, lk = lane >> 4;   // MFMA lane decomposition
  const int sr = t >> 1, sh = t & 1;          // staging row / 16-col half

  const float* ap  = xs  + (size_t)(rt*128 + sr)*DIM + sh*16;
  const us16*  bhp = wbh + (size_t)(ct*128 + sr)*DIM + sh*16;
  const us16*  blp = wbl + (size_t)(ct*128 + sr)*DIM + sh*16;

  f32x4 acc[4][4];
  #pragma unroll
  for(int m=0;m<4;m++)
    #pragma unroll
    for(int n=0;n<4;n++) acc[m][n] = (f32x4){0.f,0.f,0.f,0.f};

  float4 ar0,ar1,ar2,ar3; uint4 brh0,brh1,brl0,brl1;
  ar0 = *(const float4*)(ap+0);  ar1 = *(const float4*)(ap+4);
  ar2 = *(const float4*)(ap+8);  ar3 = *(const float4*)(ap+12);
  brh0 = *(const uint4*)(bhp);   brh1 = *(const uint4*)(bhp+8);
  brl0 = *(const uint4*)(blp);   brl1 = *(const uint4*)(blp+8);

  for(int kt=0; kt<32; kt++){
    __syncthreads();                      // prior iter's frag reads done
    {
      float fv[16];
      *(float4*)(fv+0)=ar0; *(float4*)(fv+4)=ar1;
      *(float4*)(fv+8)=ar2; *(float4*)(fv+12)=ar3;
      short8 h0,h1,l0,l1;
      #pragma unroll
      for(int j=0;j<8;j++){ short a,b; split_bf16(fv[j],a,b);   h0[j]=a; l0[j]=b; }
      #pragma unroll
      for(int j=0;j<8;j++){ short a,b; split_bf16(fv[8+j],a,b); h1[j]=a; l1[j]=b; }
      *(short8*)&Ah[sr][sh*16]   = h0;  *(short8*)&Ah[sr][sh*16+8] = h1;
      *(short8*)&Al[sr][sh*16]   = l0;  *(short8*)&Al[sr][sh*16+8] = l1;
      *(uint4*)&Bh[sr][sh*16]    = brh0; *(uint4*)&Bh[sr][sh*16+8] = brh1;
      *(uint4*)&Bl[sr][sh*16]    = brl0; *(uint4*)&Bl[sr][sh*16+8] = brl1;
    }
    __syncthreads();
    if(kt < 31){                          // prefetch next K-tile during MFMA
      const float* a2 = ap + (kt+1)*32;
      ar0 = *(const float4*)(a2+0);  ar1 = *(const float4*)(a2+4);
      ar2 = *(const float4*)(a2+8);  ar3 = *(const float4*)(a2+12);
      const us16* b2 = bhp + (kt+1)*32;
      brh0 = *(const uint4*)(b2);    brh1 = *(const uint4*)(b2+8);
      const us16* b3 = blp + (kt+1)*32;
      brl0 = *(const uint4*)(b3);    brl1 = *(const uint4*)(b3+8);
    }
    short8 fah[4], fal[4], fbh[4], fbl[4];
    #pragma unroll
    for(int m=0;m<4;m++){
      int r = wr*64 + m*16 + lm;
      fah[m] = *(const short8*)&Ah[r][lk*8];
      fal[m] = *(const short8*)&Al[r][lk*8];
    }
    #pragma unroll
    for(int n=0;n<4;n++){
      int r = wc*64 + n*16 + lm;
      fbh[n] = *(const short8*)&Bh[r][lk*8];
      fbl[n] = *(const short8*)&Bl[r][lk*8];
    }
    #pragma unroll
    for(int m=0;m<4;m++)
      #pragma unroll
      for(int n=0;n<4;n++){
        acc[m][n] = __builtin_amdgcn_mfma_f32_16x16x32_bf16(fah[m], fbh[n], acc[m][n], 0,0,0);
        acc[m][n] = __builtin_amdgcn_mfma_f32_16x16x32_bf16(fah[m], fbl[n], acc[m][n], 0,0,0);
        acc[m][n] = __builtin_amdgcn_mfma_f32_16x16x32_bf16(fal[m], fbh[n], acc[m][n], 0,0,0);
      }
  }

  // ---- epilogue: scores partial = sum_o energy[o]*tanh(a[o] + b) ----
  const int bidx = (rt*128)/NS;           // batch index, uniform per block
  float av[4], ev[4];
  #pragma unroll
  for(int n=0;n<4;n++){
    int col = ct*128 + wc*64 + n*16 + lm;
    av[n] = avec[bidx*DIM + col];
    ev[n] = energy[col];
  }
  float rs[4][4];
  #pragma unroll
  for(int m=0;m<4;m++)
    #pragma unroll
    for(int j=0;j<4;j++){
      float s = 0.f;
      #pragma unroll
      for(int n=0;n<4;n++) s += ev[n]*fast_tanh(av[n] + acc[m][n][j]);
      // reduce across the 16 lanes (lm) that share this output row
      s += __shfl_xor(s,1); s += __shfl_xor(s,2);
      s += __shfl_xor(s,4); s += __shfl_xor(s,8);
      rs[m][j] = s;
    }
  float* srow = (float*)&Ah[0][0];        // reuse LDS (after barrier)
  __syncthreads();
  if(wc==0 && lm==0){
    #pragma unroll
    for(int m=0;m<4;m++)
      #pragma unroll
      for(int j=0;j<4;j++) srow[wr*64+m*16+lk*4+j] = rs[m][j];
  }
  __syncthreads();
  if(wc==1 && lm==0){
    #pragma unroll
    for(int m=0;m<4;m++)
      #pragma unroll
      for(int j=0;j<4;j++) srow[wr*64+m*16+lk*4+j] += rs[m][j];
  }
  __syncthreads();
  if(t < 128) partial[(size_t)ct*NM + rt*128 + t] = srow[t];
}

// ---------------- reduce 8 column-tile partials -> scores ----------------
__global__ void k_reduce_scores(const float* __restrict__ partial,
                                float* __restrict__ scores){
  int i = blockIdx.x*256 + threadIdx.x;
  float s = 0.f;
  #pragma unroll
  for(int c=0;c<8;c++) s += partial[(size_t)c*NM + i];
  scores[i] = s;
}

// ---------------- masked softmax over S (one block per batch) ----------------
__global__ void k_softmax(const float* __restrict__ scores,
                          const int* __restrict__ mask,
                          float* __restrict__ attn){
  const int b = blockIdx.x, t = threadIdx.x;
  const int w = t >> 6, lane = t & 63;
  __shared__ float red[4];
  float sv[8]; int mv[8];
  float m = -3.4e38f;
  #pragma unroll
  for(int j=0;j<8;j++){
    int i = j*256 + t;
    sv[j] = scores[b*NS + i];
    mv[j] = mask[b*NS + i];
    if(mv[j] && sv[j] > m) m = sv[j];
  }
  #pragma unroll
  for(int off=1; off<64; off<<=1) m = fmaxf(m, __shfl_xor(m, off));
  if(lane==0) red[w] = m;
  __syncthreads();
  m = fmaxf(fmaxf(red[0],red[1]), fmaxf(red[2],red[3]));
  __syncthreads();
  float ev[8]; float l = 0.f;
  #pragma unroll
  for(int j=0;j<8;j++){
    ev[j] = mv[j] ? __builtin_exp2f((sv[j]-m)*1.4426950408889634f) : 0.f;
    l += ev[j];
  }
  #pragma unroll
  for(int off=1; off<64; off<<=1) l += __shfl_xor(l, off);
  if(lane==0) red[w] = l;
  __syncthreads();
  l = red[0]+red[1]+red[2]+red[3];
  float inv = 1.0f/l;
  #pragma unroll
  for(int j=0;j<8;j++) attn[b*NS + j*256 + t] = ev[j]*inv;
}

// ---------------- ctx = attn @ xs (skip negligible attn rows) ----------------
__global__ void k_ctx_partial(const float* __restrict__ attn,
                              const float* __restrict__ xs,
                              float* __restrict__ cp){
  const int b = blockIdx.x >> 3, ch = blockIdx.x & 7;
  const int t = threadIdx.x;
  __shared__ float al[256];
  al[t] = attn[b*NS + ch*256 + t];
  __syncthreads();
  float4 acc = {0.f,0.f,0.f,0.f};
  const float* base = xs + (size_t)(b*NS + ch*256)*DIM + t*4;
  for(int i=0;i<256;i++){
    float wv = al[i];                 // uniform across block -> no divergence
    if(wv > 1e-12f){                  // contribution bound < 1e-8, deterministic
      float4 x = *(const float4*)(base + (size_t)i*DIM);
      acc.x += wv*x.x; acc.y += wv*x.y; acc.z += wv*x.z; acc.w += wv*x.w;
    }
  }
  *(float4*)(cp + ((size_t)ch*NB + b)*DIM + t*4) = acc;
}

__global__ void k_ctx_reduce(const float* __restrict__ cp, float* __restrict__ ctx){
  int i = blockIdx.x*256 + threadIdx.x;
  float s = 0.f;
  #pragma unroll
  for(int ch=0; ch<8; ch++) s += cp[(size_t)ch*NB*DIM + i];
  ctx[i] = s;
}

extern "C" void kernel_launch(void* const* d_in, const int* in_sizes, int n_in,
                              void* d_out, int out_size, void* d_ws, size_t ws_size,
                              hipStream_t stream) {
  const float* kin    = (const float*)d_in[0];   // [32,1024]
  const float* xs     = (const float*)d_in[1];   // [32,2048,1024]
  const int*   mask   = (const int*)d_in[2];     // [32,2048]
  const float* wa     = (const float*)d_in[3];   // [1024,1024]
  const float* wb     = (const float*)d_in[4];   // [1024,1024]
  const float* energy = (const float*)d_in[5];   // [1024]
  float* out  = (float*)d_out;
  float* ctx  = out;            // [32,1024]
  float* attn = out + NB*DIM;   // [32,2048]

  char* ws = (char*)d_ws;
  float* partial = (float*)(ws);                          // 8*65536*4   = 2 MB
  float* avec    = (float*)(ws + 2097152);                // 32768*4     = 128 KB
  float* scores  = (float*)(ws + 2097152 + 131072);       // 65536*4     = 256 KB
  float* cp      = (float*)(ws + 2097152 + 393216);       // 8*32768*4   = 1 MB
  us16*  wbh     = (us16*) (ws + 2097152 + 1441792);      // 1M*2        = 2 MB
  us16*  wbl     = (us16*) (ws + 2097152 + 1441792 + 2097152); // 2 MB  (total ~7.4 MB)

  k_split_wb     <<<512, 256, 0, stream>>>(wb, wbh, wbl);
  k_compute_a    <<<128, 256, 0, stream>>>(kin, wa, avec);
  k_gemm_scores  <<<4096, 256, 0, stream>>>(xs, wbh, wbl, avec, energy, partial);
  k_reduce_scores<<<256, 256, 0, stream>>>(partial, scores);
  k_softmax      <<<NB, 256, 0, stream>>>(scores, mask, attn);
  k_ctx_partial  <<<256, 256, 0, stream>>>(attn, xs, cp);
  k_ctx_reduce   <<<128, 256, 0, stream>>>(cp, ctx);
}